// Round 14
// baseline (181.096 us; speedup 1.0000x reference)
//
#include <hip/hip_runtime.h>
#include <math.h>

#define Bn 2
#define Hn 8
#define Nn 256
#define Dn 64
#define BH 16
#define SCALER 0.125f

typedef _Float16 half8 __attribute__((ext_vector_type(8)));
typedef _Float16 half4 __attribute__((ext_vector_type(4)));
typedef float floatx4 __attribute__((ext_vector_type(4)));
typedef float floatx16 __attribute__((ext_vector_type(16)));

__device__ __forceinline__ void split_f32(float v, _Float16& h, _Float16& l) {
    h = (_Float16)v;
    l = (_Float16)(v - (float)h);
}

__device__ __forceinline__ void split8(const float4& v0, const float4& v1,
                                       half8& h, half8& l) {
    const float vv[8] = {v0.x, v0.y, v0.z, v0.w, v1.x, v1.y, v1.z, v1.w};
    #pragma unroll
    for (int e = 0; e < 8; ++e) {
        _Float16 hh, ll;
        split_f32(vv[e], hh, ll);
        h[e] = hh; l[e] = ll;
    }
}

// ---------------------------------------------------------------------------
// Fused split of x (blocks 0..255) and w (blocks 256..1535) to f16 hi/lo.
// ---------------------------------------------------------------------------
__global__ __launch_bounds__(256) void split2_kernel(
    const float* __restrict__ x, const float* __restrict__ w,
    _Float16* __restrict__ xh, _Float16* __restrict__ xl,
    _Float16* __restrict__ wh, _Float16* __restrict__ wl) {
    const int b = blockIdx.x;
    const float* src;
    _Float16 *hp, *lp;
    int idx;
    if (b < 256) {
        idx = (b * 256 + threadIdx.x) * 4;
        src = x; hp = xh; lp = xl;
    } else {
        idx = ((b - 256) * 256 + threadIdx.x) * 4;
        src = w; hp = wh; lp = wl;
    }
    const float4 v = *(const float4*)(src + idx);
    half4 hh, ll;
    _Float16 a2, b2;
    split_f32(v.x, a2, b2); hh[0] = a2; ll[0] = b2;
    split_f32(v.y, a2, b2); hh[1] = a2; ll[1] = b2;
    split_f32(v.z, a2, b2); hh[2] = a2; ll[2] = b2;
    split_f32(v.w, a2, b2); hh[3] = a2; ll[3] = b2;
    *(half4*)(hp + idx) = hh;
    *(half4*)(lp + idx) = ll;
}

// ---------------------------------------------------------------------------
// Projection, pre-split inputs, pure loads. Tile 64m x 64r, grid (8, 40).
// Blocks with blockIdx.y >= 32 (s=4, vk) write vkT directly (R13).
// ---------------------------------------------------------------------------
__global__ __launch_bounds__(256) void proj_mfma(
    const _Float16* __restrict__ xh, const _Float16* __restrict__ xl,
    const _Float16* __restrict__ wh, const _Float16* __restrict__ wl,
    float* __restrict__ P32, float* __restrict__ vkT) {
    const int m0 = blockIdx.x * 64;
    const int r0 = blockIdx.y * 64;
    const int t = threadIdx.x;
    const int w = t >> 6, l = t & 63;
    const int lr = l & 15, kk8 = (l >> 4) * 8;

    floatx4 acc[4];
    #pragma unroll
    for (int ni = 0; ni < 4; ++ni) acc[ni] = (floatx4){0.f, 0.f, 0.f, 0.f};

    const int arow = m0 + w * 16 + lr;
    for (int kt = 0; kt < 16; ++kt) {
        const int k0 = kt * 32 + kk8;
        const half8 ah = *(const half8*)(xh + arow * 512 + k0);
        const half8 al = *(const half8*)(xl + arow * 512 + k0);
        half8 bhv[4], blv[4];
        #pragma unroll
        for (int ni = 0; ni < 4; ++ni) {
            const int wr = r0 + ni * 16 + lr;
            bhv[ni] = *(const half8*)(wh + wr * 512 + k0);
            blv[ni] = *(const half8*)(wl + wr * 512 + k0);
        }
        #pragma unroll
        for (int ni = 0; ni < 4; ++ni)
            acc[ni] = __builtin_amdgcn_mfma_f32_16x16x32_f16(ah, bhv[ni], acc[ni], 0, 0, 0);
        #pragma unroll
        for (int ni = 0; ni < 4; ++ni)
            acc[ni] = __builtin_amdgcn_mfma_f32_16x16x32_f16(ah, blv[ni], acc[ni], 0, 0, 0);
        #pragma unroll
        for (int ni = 0; ni < 4; ++ni)
            acc[ni] = __builtin_amdgcn_mfma_f32_16x16x32_f16(al, bhv[ni], acc[ni], 0, 0, 0);
    }
    const int rbase = (l >> 4) * 4;
    if (blockIdx.y >= 32) {
        const int mbase = m0 + w * 16 + rbase;
        const int b = mbase >> 8, n = mbase & 255;
        #pragma unroll
        for (int ni = 0; ni < 4; ++ni) {
            const int rcol = r0 + ni * 16 + lr;
            const int h = (rcol >> 6) & 7, d = rcol & 63;
            *(float4*)(vkT + (((b * 8 + h) * 64 + d) * 256 + n)) =
                (float4){acc[ni][0], acc[ni][1], acc[ni][2], acc[ni][3]};
        }
        return;
    }
    #pragma unroll
    for (int ni = 0; ni < 4; ++ni) {
        const int rcol = r0 + ni * 16 + lr;
        const int s = rcol >> 9, h = (rcol >> 6) & 7, d = rcol & 63;
        #pragma unroll
        for (int r = 0; r < 4; ++r) {
            const int m = m0 + w * 16 + rbase + r;
            const int b = m >> 8, n = m & 255;
            P32[(((s * 2 + b) * 8 + h) * 256 + n) * 64 + d] = acc[ni][r];
        }
    }
}

// ---------------------------------------------------------------------------
// Scores + fused exp. Stabilization shifts dropped (cancel exactly).
// ---------------------------------------------------------------------------
__global__ __launch_bounds__(256) void score_vkt(
    const float* __restrict__ P32,
    _Float16* __restrict__ Xsh, _Float16* __restrict__ Xsl,
    float* __restrict__ Yt, float* __restrict__ Z) {
    const int bh = blockIdx.x, mat = blockIdx.y;
    const int t = threadIdx.x;
    const int i0 = (blockIdx.z >> 2) * 128;
    const int j0 = (blockIdx.z & 3) * 64;
    const int w = t >> 6, l = t & 63;
    const int lr = l & 15, kk8 = (l >> 4) * 8;
    const float* A;
    const float* Bm;
    if (mat == 0)      { A = P32 + (1 * 16 + bh) * 16384; Bm = P32 + (2 * 16 + bh) * 16384; }
    else if (mat == 1) { A = P32 + (0 * 16 + bh) * 16384; Bm = P32 + (2 * 16 + bh) * 16384; }
    else               { A = P32 + (0 * 16 + bh) * 16384; Bm = P32 + (1 * 16 + bh) * 16384; }

    floatx4 acc[2][4];
    #pragma unroll
    for (int mi = 0; mi < 2; ++mi)
        #pragma unroll
        for (int ni = 0; ni < 4; ++ni) acc[mi][ni] = (floatx4){0.f, 0.f, 0.f, 0.f};

    for (int kt = 0; kt < 2; ++kt) {
        const int k0 = kt * 32 + kk8;
        half8 ah[2], al[2], bh8[4], bl8[4];
        #pragma unroll
        for (int mi = 0; mi < 2; ++mi) {
            const int row = i0 + w * 32 + mi * 16 + lr;
            const float4 v0 = *(const float4*)(A + row * 64 + k0);
            const float4 v1 = *(const float4*)(A + row * 64 + k0 + 4);
            split8(v0, v1, ah[mi], al[mi]);
        }
        #pragma unroll
        for (int ni = 0; ni < 4; ++ni) {
            const int row = j0 + ni * 16 + lr;
            const float4 v0 = *(const float4*)(Bm + row * 64 + k0);
            const float4 v1 = *(const float4*)(Bm + row * 64 + k0 + 4);
            split8(v0, v1, bh8[ni], bl8[ni]);
        }
        #pragma unroll
        for (int mi = 0; mi < 2; ++mi)
            #pragma unroll
            for (int ni = 0; ni < 4; ++ni)
                acc[mi][ni] = __builtin_amdgcn_mfma_f32_16x16x32_f16(ah[mi], bh8[ni], acc[mi][ni], 0, 0, 0);
        #pragma unroll
        for (int mi = 0; mi < 2; ++mi)
            #pragma unroll
            for (int ni = 0; ni < 4; ++ni)
                acc[mi][ni] = __builtin_amdgcn_mfma_f32_16x16x32_f16(ah[mi], bl8[ni], acc[mi][ni], 0, 0, 0);
        #pragma unroll
        for (int mi = 0; mi < 2; ++mi)
            #pragma unroll
            for (int ni = 0; ni < 4; ++ni)
                acc[mi][ni] = __builtin_amdgcn_mfma_f32_16x16x32_f16(al[mi], bh8[ni], acc[mi][ni], 0, 0, 0);
    }
    const int rbase = (l >> 4) * 4;
    #pragma unroll
    for (int mi = 0; mi < 2; ++mi)
        #pragma unroll
        for (int ni = 0; ni < 4; ++ni)
            #pragma unroll
            for (int r = 0; r < 4; ++r) {
                const int row = i0 + w * 32 + mi * 16 + rbase + r;
                const int col = j0 + ni * 16 + lr;
                const float e = expf(acc[mi][ni][r] * SCALER);
                if (mat == 0) {
                    const int idx = (bh * 256 + row) * 256 + col;
                    _Float16 hh, ll; split_f32(e, hh, ll);
                    Xsh[idx] = hh; Xsl[idx] = ll;
                } else if (mat == 1) {
                    Yt[bh * 65536 + row * 256 + col] = e;
                } else {
                    Z[bh * 65536 + row * 256 + col] = e;
                }
            }
}

// ---------------------------------------------------------------------------
// Den. grid (16,16): bh x 16-row i-tile. 4 waves split 16 jt-groups.
// ---------------------------------------------------------------------------
__global__ __launch_bounds__(256) void den_mfma(
    const float* __restrict__ Yt, const _Float16* __restrict__ Xh,
    const _Float16* __restrict__ Xl, const float* __restrict__ Z,
    float* __restrict__ Den) {
    const int bh = blockIdx.x;
    const int ibase = blockIdx.y * 16;
    const int t = threadIdx.x;
    const int w = t >> 6, l = t & 63;
    const int lr = l & 15, ks = l >> 4, kk8 = ks * 8;
    const float* Ytp = Yt + bh * 65536;
    const _Float16* Xhp = Xh + bh * 65536;
    const _Float16* Xlp = Xl + bh * 65536;

    floatx4 acc[4];
    #pragma unroll
    for (int q = 0; q < 4; ++q) acc[q] = (floatx4){0.f, 0.f, 0.f, 0.f};

    for (int kt = 0; kt < 8; ++kt) {
        const int k0 = kt * 32 + kk8;
        half8 ah, al;
        {
            const float4 v0 = *(const float4*)(Ytp + (ibase + lr) * 256 + k0);
            const float4 v1 = *(const float4*)(Ytp + (ibase + lr) * 256 + k0 + 4);
            split8(v0, v1, ah, al);
        }
        half8 bh8[4], bl8[4];
        #pragma unroll
        for (int q = 0; q < 4; ++q) {
            const int jt = w * 4 + q;
            bh8[q] = *(const half8*)(Xhp + (jt * 16 + lr) * 256 + k0);
            bl8[q] = *(const half8*)(Xlp + (jt * 16 + lr) * 256 + k0);
        }
        #pragma unroll
        for (int q = 0; q < 4; ++q)
            acc[q] = __builtin_amdgcn_mfma_f32_16x16x32_f16(ah, bh8[q], acc[q], 0, 0, 0);
        #pragma unroll
        for (int q = 0; q < 4; ++q)
            acc[q] = __builtin_amdgcn_mfma_f32_16x16x32_f16(ah, bl8[q], acc[q], 0, 0, 0);
        #pragma unroll
        for (int q = 0; q < 4; ++q)
            acc[q] = __builtin_amdgcn_mfma_f32_16x16x32_f16(al, bh8[q], acc[q], 0, 0, 0);
    }
    __shared__ float redS[4][16];
    float dp[4] = {0.f, 0.f, 0.f, 0.f};
    const float* Zp = Z + (bh * 256 + ibase) * 256;
    #pragma unroll
    for (int q = 0; q < 4; ++q) {
        const int jt = w * 4 + q;
        #pragma unroll
        for (int r = 0; r < 4; ++r)
            dp[r] += acc[q][r] * Zp[(ks * 4 + r) * 256 + jt * 16 + lr];
    }
    #pragma unroll
    for (int r = 0; r < 4; ++r) {
        float s = dp[r];
        s += __shfl_xor(s, 1); s += __shfl_xor(s, 2);
        s += __shfl_xor(s, 4); s += __shfl_xor(s, 8);
        if (lr == 0) redS[w][ks * 4 + r] = s;
    }
    __syncthreads();
    if (t < 16)
        Den[bh * 256 + ibase + t] =
            redS[0][t] + redS[1][t] + redS[2][t] + redS[3][t] + 1e-9f;
}

// ---------------------------------------------------------------------------
// Main contraction — R21: R20 (32x32x16 fragments on the R16 skeleton) with
// the B-LDS layout changed from 16B granules to SPLIT b64 units to kill the
// measured 4.19M 4-way bank conflict:
//   unit(d, o, half) = half*8 + (o ^ (d&7)); addr = d*128B + unit*8B.
// Read (ds_read_b64, fixed half): 64 lanes -> 8 bank-pairs x 8 lanes =
// 2-way over floor (free, m136). Write: same, 2-way. The two halves of a
// fragment are 64 B apart -> compiler CANNOT fuse them back into b128
// (fusing any adjacent-pair layout would reintroduce the 4-way: bank group
// of a 16B granule is a 3-bit function of d, and 32 distinct d rows per
// instruction make >=4-way unavoidable at 16B granularity).
// All else R20 verbatim: schedule, vmcnt(16), A-map (row=l&31, k-oct=l>>5),
// C/D map (col=lane&31, row=(r&3)+8*(r>>2)+4*(lane>>5)). Epilogue cleaned.
// ---------------------------------------------------------------------------
__global__ __launch_bounds__(256, 2) void attn_mfma(
    const _Float16* __restrict__ Xh, const _Float16* __restrict__ Xl,
    const float* __restrict__ Yt, const float* __restrict__ Z,
    const float* __restrict__ vkT, const float* __restrict__ P32,
    const float* __restrict__ Den, float* __restrict__ out) {
    const int id = (blockIdx.x & 7) * 256 + (blockIdx.x >> 3);  // XCD swizzle
    const int bh = id >> 7;
    const int i0 = (id & 127) * 2;
    const int t = threadIdx.x;
    const int w = t >> 6, l = t & 63;
    const int l31 = l & 31, lh = l >> 5;                       // 32-row lane map

    __shared__ float yiS[2][256], ziS[2][256];                 // 4 KB
    __shared__ _Float16 BhS[2][2][4096], BlS[2][2][4096];      // 64 KB
    // redN aliases yiS (2 KB). Safe: last yiS read is BSTORE(3) in step 2,
    // which precedes step-2's barrier; epilogue runs after the final steps.
    float (*redN)[2][64] = reinterpret_cast<float (*)[2][64]>(&yiS[0][0]);

    yiS[0][t] = Yt[(bh * 256 + i0) * 256 + t];
    yiS[1][t] = Yt[(bh * 256 + i0 + 1) * 256 + t];
    ziS[0][t] = Z[(bh * 256 + i0) * 256 + t];
    ziS[1][t] = Z[(bh * 256 + i0 + 1) * 256 + t];

    const _Float16* Xhp = Xh + bh * 65536;
    const _Float16* Xlp = Xl + bh * 65536;
    const float* vkp = vkT + bh * 16384;
    const float* vj = P32 + (3 * 16 + bh) * 16384;

    floatx16 acc[2][4];
    #pragma unroll
    for (int mi = 0; mi < 2; ++mi)
        #pragma unroll
        for (int ct = 0; ct < 4; ++ct)
            #pragma unroll
            for (int r = 0; r < 16; ++r) acc[mi][ct][r] = 0.f;

    // VKLOAD/BSTORE thread map: d = t>>2 (64 rows), sl = t&3 (16-k slice)
    const int vd = t >> 2;
    const int sl = t & 3;
    float4 vkr[4];                        // in-flight vk slice (16 f32)

    // ---- VKLOAD: vk[vd][kt*64 + sl*16 .. +15] -> vkr (4 x dwordx4)
    auto VKLOAD = [&](int kt) {
        const float* gp = vkp + vd * 256 + (kt & 3) * 64 + sl * 16;
        #pragma unroll
        for (int q = 0; q < 4; ++q) vkr[q] = *(const float4*)(gp + q * 4);
    };
    // ---- BSTORE: vkr * y -> split -> split-b64 layout in BhS/BlS[(ktb)&1]
    auto BSTORE = [&](int ktb) {
        const int buf = ktb & 1;
        #pragma unroll
        for (int i = 0; i < 2; ++i) {
            const float* yrow = &yiS[i][(ktb & 3) * 64 + sl * 16];
            #pragma unroll
            for (int hq = 0; hq < 2; ++hq) {          // octet pair
                const float4 va = vkr[hq * 2], vb = vkr[hq * 2 + 1];
                const float4 ya = *(const float4*)(yrow + hq * 8);
                const float4 yb = *(const float4*)(yrow + hq * 8 + 4);
                const float pv[8] = {va.x * ya.x, va.y * ya.y, va.z * ya.z, va.w * ya.w,
                                     vb.x * yb.x, vb.y * yb.y, vb.z * yb.z, vb.w * yb.w};
                half4 hv[2], lv[2];
                #pragma unroll
                for (int e = 0; e < 8; ++e) {
                    _Float16 hh, ll;
                    split_f32(pv[e], hh, ll);
                    hv[e >> 2][e & 3] = hh; lv[e >> 2][e & 3] = ll;
                }
                const int o = sl * 2 + hq;            // k-octet 0..7 in 64-k tile
                const int gx = o ^ (vd & 7);
                #pragma unroll
                for (int hf2 = 0; hf2 < 2; ++hf2) {
                    const int off = vd * 64 + (hf2 * 8 + gx) * 4;
                    *(half4*)&BhS[buf][i][off] = hv[hf2];
                    *(half4*)&BlS[buf][i][off] = lv[hf2];
                }
            }
        }
    };
    // ---- LOADA: X frags, 32x32x16 layout: row = w*64 + mi*32 + l31,
    //      k = (kt&3)*64 + sub*32 + kb*16 + lh*8  (8 half8 loads h + l)
    auto LOADA = [&](half8 (&AH)[2][2], half8 (&AL)[2][2], int kt, int sub) {
        const int k0 = (kt & 3) * 64 + sub * 32 + lh * 8;
        #pragma unroll
        for (int mi = 0; mi < 2; ++mi) {
            const int row = w * 64 + mi * 32 + l31;
            #pragma unroll
            for (int kb = 0; kb < 2; ++kb) {
                const int kk = k0 + kb * 16;
                AH[mi][kb] = *(const half8*)(Xhp + row * 256 + kk);
                AL[mi][kb] = *(const half8*)(Xlp + row * 256 + kk);
            }
        }
    };
    auto MFMA_STEP = [&](half8 (&AH)[2][2], half8 (&AL)[2][2], int buf, int sub) {
        __builtin_amdgcn_s_setprio(1);
        #pragma unroll
        for (int ct = 0; ct < 4; ++ct) {
            const int ii = ct >> 1;
            const int d = (ct & 1) * 32 + l31;
            #pragma unroll
            for (int kb = 0; kb < 2; ++kb) {
                const int o = sub * 4 + kb * 2 + lh;
                const int gx = o ^ (d & 7);
                const int off0 = d * 64 + gx * 4;          // half 0 (64 B apart)
                const int off1 = d * 64 + (8 + gx) * 4;    // half 1
                const half4 bh0 = *(const half4*)&BhS[buf][ii][off0];
                const half4 bh1 = *(const half4*)&BhS[buf][ii][off1];
                const half4 bl0 = *(const half4*)&BlS[buf][ii][off0];
                const half4 bl1 = *(const half4*)&BlS[buf][ii][off1];
                half8 bhf, blf;
                #pragma unroll
                for (int e = 0; e < 4; ++e) {
                    bhf[e] = bh0[e]; bhf[4 + e] = bh1[e];
                    blf[e] = bl0[e]; blf[4 + e] = bl1[e];
                }
                #pragma unroll
                for (int mi = 0; mi < 2; ++mi)
                    acc[mi][ct] = __builtin_amdgcn_mfma_f32_32x32x16_f16(AH[mi][kb], bhf, acc[mi][ct], 0, 0, 0);
                #pragma unroll
                for (int mi = 0; mi < 2; ++mi)
                    acc[mi][ct] = __builtin_amdgcn_mfma_f32_32x32x16_f16(AH[mi][kb], blf, acc[mi][ct], 0, 0, 0);
                #pragma unroll
                for (int mi = 0; mi < 2; ++mi)
                    acc[mi][ct] = __builtin_amdgcn_mfma_f32_32x32x16_f16(AL[mi][kb], bhf, acc[mi][ct], 0, 0, 0);
            }
        }
        __builtin_amdgcn_s_setprio(0);
    };

    half8 A0h[2][2], A0l[2][2], A1h[2][2], A1l[2][2];

    // ---- prologue: vk(0) in regs, A(0,sub0); build B(0)
    VKLOAD(0);                                   // 4 vmem
    LOADA(A0h, A0l, 0, 0);                       // 8 vmem
    __syncthreads();                             // drains all vmem/lgkm; y/z visible
    BSTORE(0);
    __syncthreads();                             // B(0) visible

    // ---- main loop: steps 0..2 full; step 3 tail (R16 schedule verbatim)
    #pragma unroll 1
    for (int kt = 0; kt < 3; ++kt) {
        const int buf = kt & 1;
        VKLOAD(kt + 1);                          // 4 vmem
        LOADA(A1h, A1l, kt, 1);                  // 8 vmem
        MFMA_STEP(A0h, A0l, buf, 0);             // reads BhS[buf]
        LOADA(A0h, A0l, kt + 1, 0);              // 8 vmem (next step's sub0)
        MFMA_STEP(A1h, A1l, buf, 1);             // covers loads
        asm volatile("s_waitcnt vmcnt(16)" ::: "memory");  // VKLOAD(kt+1) landed
        __builtin_amdgcn_sched_barrier(0);
        BSTORE(kt + 1);                          // writes BhS[buf^1]
        __syncthreads();
    }
    // tail: kt = 3 (buf 1)
    LOADA(A1h, A1l, 3, 1);
    MFMA_STEP(A0h, A0l, 1, 0);
    MFMA_STEP(A1h, A1l, 1, 1);

    // ---- epilogue: C/D map col=l&31 (-> d), row=(r&3)+8*(r>>2)+4*lh (-> j)
    #pragma unroll
    for (int ct = 0; ct < 4; ++ct) {
        const int ii = ct >> 1;
        const int d = (ct & 1) * 32 + l31;
        float n = 0.f;
        #pragma unroll
        for (int mi = 0; mi < 2; ++mi)
            #pragma unroll
            for (int r = 0; r < 16; ++r) {
                const int jl = (r & 3) + 8 * (r >> 2) + 4 * lh;
                const int j = w * 64 + mi * 32 + jl;
                n += acc[mi][ct][r] * ziS[ii][j] * vj[j * 64 + d];
            }
        n += __shfl_xor(n, 32);
        if (l < 32) redN[w][ii][d] = n;
    }
    __syncthreads();
    if (t < 128) {
        const int ih = t >> 6, d = t & 63;
        const float num = redN[0][ih][d] + redN[1][ih][d] +
                          redN[2][ih][d] + redN[3][ih][d];
        const int i = i0 + ih;
        const float den = Den[bh * 256 + i];
        out[((bh >> 3) * 256 + i) * 512 + (bh & 7) * 64 + d] = num / den;
    }
}

extern "C" void kernel_launch(void* const* d_in, const int* in_sizes, int n_in,
                              void* d_out, int out_size, void* d_ws, size_t ws_size,
                              hipStream_t stream) {
    const float* x = (const float*)d_in[0];
    const float* w = (const float*)d_in[1];
    float* out = (float*)d_out;

    float* ws = (float*)d_ws;
    float* P32 = ws;                                    // 1,310,720 f32
    float* U = ws + 1310720;
    // epoch A (proj inputs, dead after proj):
    _Float16* xh = (_Float16*)U;
    _Float16* xl = xh + 262144;
    _Float16* wh = xl + 262144;
    _Float16* wl = wh + 1310720;
    // epoch B (score onward):
    _Float16* Xsh = (_Float16*)U;                       // 1,048,576 h
    _Float16* Xsl = Xsh + 1048576;
    float* Yt = U + 1048576;                            // 1,048,576 f32
    float* Z = Yt + 1048576;                            // 1,048,576 f32
    float* vkT = Z + 1048576;                           // 262,144 f32 (written by proj)
    float* Den = vkT + 262144;                          // 4,096 f32

    split2_kernel<<<1536, 256, 0, stream>>>(x, w, xh, xl, wh, wl);
    proj_mfma<<<dim3(8, 40), 256, 0, stream>>>(xh, xl, wh, wl, P32, vkT);
    score_vkt<<<dim3(16, 3, 8), 256, 0, stream>>>(P32, Xsh, Xsl, Yt, Z);
    den_mfma<<<dim3(16, 16), 256, 0, stream>>>(Yt, Xsh, Xsl, Z, Den);
    attn_mfma<<<2048, 256, 0, stream>>>(Xsh, Xsl, Yt, Z, vkT, P32, Den, out);
}

// Round 15
// 169.444 us; speedup vs baseline: 1.0688x; 1.0688x over previous
//
#include <hip/hip_runtime.h>
#include <math.h>

#define Bn 2
#define Hn 8
#define Nn 256
#define Dn 64
#define BH 16
#define SCALER 0.125f

typedef _Float16 half8 __attribute__((ext_vector_type(8)));
typedef _Float16 half4 __attribute__((ext_vector_type(4)));
typedef float floatx4 __attribute__((ext_vector_type(4)));

__device__ __forceinline__ void split_f32(float v, _Float16& h, _Float16& l) {
    h = (_Float16)v;
    l = (_Float16)(v - (float)h);
}

__device__ __forceinline__ void split8(const float4& v0, const float4& v1,
                                       half8& h, half8& l) {
    const float vv[8] = {v0.x, v0.y, v0.z, v0.w, v1.x, v1.y, v1.z, v1.w};
    #pragma unroll
    for (int e = 0; e < 8; ++e) {
        _Float16 hh, ll;
        split_f32(vv[e], hh, ll);
        h[e] = hh; l[e] = ll;
    }
}

// ---------------------------------------------------------------------------
// Fused split of x (blocks 0..255) and w (blocks 256..1535) to f16 hi/lo.
// ---------------------------------------------------------------------------
__global__ __launch_bounds__(256) void split2_kernel(
    const float* __restrict__ x, const float* __restrict__ w,
    _Float16* __restrict__ xh, _Float16* __restrict__ xl,
    _Float16* __restrict__ wh, _Float16* __restrict__ wl) {
    const int b = blockIdx.x;
    const float* src;
    _Float16 *hp, *lp;
    int idx;
    if (b < 256) {
        idx = (b * 256 + threadIdx.x) * 4;
        src = x; hp = xh; lp = xl;
    } else {
        idx = ((b - 256) * 256 + threadIdx.x) * 4;
        src = w; hp = wh; lp = wl;
    }
    const float4 v = *(const float4*)(src + idx);
    half4 hh, ll;
    _Float16 a2, b2;
    split_f32(v.x, a2, b2); hh[0] = a2; ll[0] = b2;
    split_f32(v.y, a2, b2); hh[1] = a2; ll[1] = b2;
    split_f32(v.z, a2, b2); hh[2] = a2; ll[2] = b2;
    split_f32(v.w, a2, b2); hh[3] = a2; ll[3] = b2;
    *(half4*)(hp + idx) = hh;
    *(half4*)(lp + idx) = ll;
}

// ---------------------------------------------------------------------------
// Projection, pre-split inputs, pure loads. Tile 64m x 64r, grid (8, 40).
// Blocks with blockIdx.y >= 32 (s=4, vk) write vkT directly (R13).
// ---------------------------------------------------------------------------
__global__ __launch_bounds__(256) void proj_mfma(
    const _Float16* __restrict__ xh, const _Float16* __restrict__ xl,
    const _Float16* __restrict__ wh, const _Float16* __restrict__ wl,
    float* __restrict__ P32, float* __restrict__ vkT) {
    const int m0 = blockIdx.x * 64;
    const int r0 = blockIdx.y * 64;
    const int t = threadIdx.x;
    const int w = t >> 6, l = t & 63;
    const int lr = l & 15, kk8 = (l >> 4) * 8;

    floatx4 acc[4];
    #pragma unroll
    for (int ni = 0; ni < 4; ++ni) acc[ni] = (floatx4){0.f, 0.f, 0.f, 0.f};

    const int arow = m0 + w * 16 + lr;
    for (int kt = 0; kt < 16; ++kt) {
        const int k0 = kt * 32 + kk8;
        const half8 ah = *(const half8*)(xh + arow * 512 + k0);
        const half8 al = *(const half8*)(xl + arow * 512 + k0);
        half8 bhv[4], blv[4];
        #pragma unroll
        for (int ni = 0; ni < 4; ++ni) {
            const int wr = r0 + ni * 16 + lr;
            bhv[ni] = *(const half8*)(wh + wr * 512 + k0);
            blv[ni] = *(const half8*)(wl + wr * 512 + k0);
        }
        #pragma unroll
        for (int ni = 0; ni < 4; ++ni)
            acc[ni] = __builtin_amdgcn_mfma_f32_16x16x32_f16(ah, bhv[ni], acc[ni], 0, 0, 0);
        #pragma unroll
        for (int ni = 0; ni < 4; ++ni)
            acc[ni] = __builtin_amdgcn_mfma_f32_16x16x32_f16(ah, blv[ni], acc[ni], 0, 0, 0);
        #pragma unroll
        for (int ni = 0; ni < 4; ++ni)
            acc[ni] = __builtin_amdgcn_mfma_f32_16x16x32_f16(al, bhv[ni], acc[ni], 0, 0, 0);
    }
    const int rbase = (l >> 4) * 4;
    if (blockIdx.y >= 32) {
        const int mbase = m0 + w * 16 + rbase;
        const int b = mbase >> 8, n = mbase & 255;
        #pragma unroll
        for (int ni = 0; ni < 4; ++ni) {
            const int rcol = r0 + ni * 16 + lr;
            const int h = (rcol >> 6) & 7, d = rcol & 63;
            *(float4*)(vkT + (((b * 8 + h) * 64 + d) * 256 + n)) =
                (float4){acc[ni][0], acc[ni][1], acc[ni][2], acc[ni][3]};
        }
        return;
    }
    #pragma unroll
    for (int ni = 0; ni < 4; ++ni) {
        const int rcol = r0 + ni * 16 + lr;
        const int s = rcol >> 9, h = (rcol >> 6) & 7, d = rcol & 63;
        #pragma unroll
        for (int r = 0; r < 4; ++r) {
            const int m = m0 + w * 16 + rbase + r;
            const int b = m >> 8, n = m & 255;
            P32[(((s * 2 + b) * 8 + h) * 256 + n) * 64 + d] = acc[ni][r];
        }
    }
}

// ---------------------------------------------------------------------------
// Scores + fused exp. Stabilization shifts dropped (cancel exactly).
// ---------------------------------------------------------------------------
__global__ __launch_bounds__(256) void score_vkt(
    const float* __restrict__ P32,
    _Float16* __restrict__ Xsh, _Float16* __restrict__ Xsl,
    float* __restrict__ Yt, float* __restrict__ Z) {
    const int bh = blockIdx.x, mat = blockIdx.y;
    const int t = threadIdx.x;
    const int i0 = (blockIdx.z >> 2) * 128;
    const int j0 = (blockIdx.z & 3) * 64;
    const int w = t >> 6, l = t & 63;
    const int lr = l & 15, kk8 = (l >> 4) * 8;
    const float* A;
    const float* Bm;
    if (mat == 0)      { A = P32 + (1 * 16 + bh) * 16384; Bm = P32 + (2 * 16 + bh) * 16384; }
    else if (mat == 1) { A = P32 + (0 * 16 + bh) * 16384; Bm = P32 + (2 * 16 + bh) * 16384; }
    else               { A = P32 + (0 * 16 + bh) * 16384; Bm = P32 + (1 * 16 + bh) * 16384; }

    floatx4 acc[2][4];
    #pragma unroll
    for (int mi = 0; mi < 2; ++mi)
        #pragma unroll
        for (int ni = 0; ni < 4; ++ni) acc[mi][ni] = (floatx4){0.f, 0.f, 0.f, 0.f};

    for (int kt = 0; kt < 2; ++kt) {
        const int k0 = kt * 32 + kk8;
        half8 ah[2], al[2], bh8[4], bl8[4];
        #pragma unroll
        for (int mi = 0; mi < 2; ++mi) {
            const int row = i0 + w * 32 + mi * 16 + lr;
            const float4 v0 = *(const float4*)(A + row * 64 + k0);
            const float4 v1 = *(const float4*)(A + row * 64 + k0 + 4);
            split8(v0, v1, ah[mi], al[mi]);
        }
        #pragma unroll
        for (int ni = 0; ni < 4; ++ni) {
            const int row = j0 + ni * 16 + lr;
            const float4 v0 = *(const float4*)(Bm + row * 64 + k0);
            const float4 v1 = *(const float4*)(Bm + row * 64 + k0 + 4);
            split8(v0, v1, bh8[ni], bl8[ni]);
        }
        #pragma unroll
        for (int mi = 0; mi < 2; ++mi)
            #pragma unroll
            for (int ni = 0; ni < 4; ++ni)
                acc[mi][ni] = __builtin_amdgcn_mfma_f32_16x16x32_f16(ah[mi], bh8[ni], acc[mi][ni], 0, 0, 0);
        #pragma unroll
        for (int mi = 0; mi < 2; ++mi)
            #pragma unroll
            for (int ni = 0; ni < 4; ++ni)
                acc[mi][ni] = __builtin_amdgcn_mfma_f32_16x16x32_f16(ah[mi], bl8[ni], acc[mi][ni], 0, 0, 0);
        #pragma unroll
        for (int mi = 0; mi < 2; ++mi)
            #pragma unroll
            for (int ni = 0; ni < 4; ++ni)
                acc[mi][ni] = __builtin_amdgcn_mfma_f32_16x16x32_f16(al[mi], bh8[ni], acc[mi][ni], 0, 0, 0);
    }
    const int rbase = (l >> 4) * 4;
    #pragma unroll
    for (int mi = 0; mi < 2; ++mi)
        #pragma unroll
        for (int ni = 0; ni < 4; ++ni)
            #pragma unroll
            for (int r = 0; r < 4; ++r) {
                const int row = i0 + w * 32 + mi * 16 + rbase + r;
                const int col = j0 + ni * 16 + lr;
                const float e = expf(acc[mi][ni][r] * SCALER);
                if (mat == 0) {
                    const int idx = (bh * 256 + row) * 256 + col;
                    _Float16 hh, ll; split_f32(e, hh, ll);
                    Xsh[idx] = hh; Xsl[idx] = ll;
                } else if (mat == 1) {
                    Yt[bh * 65536 + row * 256 + col] = e;
                } else {
                    Z[bh * 65536 + row * 256 + col] = e;
                }
            }
}

// ---------------------------------------------------------------------------
// Den. grid (16,16): bh x 16-row i-tile. 4 waves split 16 jt-groups.
// ---------------------------------------------------------------------------
__global__ __launch_bounds__(256) void den_mfma(
    const float* __restrict__ Yt, const _Float16* __restrict__ Xh,
    const _Float16* __restrict__ Xl, const float* __restrict__ Z,
    float* __restrict__ Den) {
    const int bh = blockIdx.x;
    const int ibase = blockIdx.y * 16;
    const int t = threadIdx.x;
    const int w = t >> 6, l = t & 63;
    const int lr = l & 15, ks = l >> 4, kk8 = ks * 8;
    const float* Ytp = Yt + bh * 65536;
    const _Float16* Xhp = Xh + bh * 65536;
    const _Float16* Xlp = Xl + bh * 65536;

    floatx4 acc[4];
    #pragma unroll
    for (int q = 0; q < 4; ++q) acc[q] = (floatx4){0.f, 0.f, 0.f, 0.f};

    for (int kt = 0; kt < 8; ++kt) {
        const int k0 = kt * 32 + kk8;
        half8 ah, al;
        {
            const float4 v0 = *(const float4*)(Ytp + (ibase + lr) * 256 + k0);
            const float4 v1 = *(const float4*)(Ytp + (ibase + lr) * 256 + k0 + 4);
            split8(v0, v1, ah, al);
        }
        half8 bh8[4], bl8[4];
        #pragma unroll
        for (int q = 0; q < 4; ++q) {
            const int jt = w * 4 + q;
            bh8[q] = *(const half8*)(Xhp + (jt * 16 + lr) * 256 + k0);
            bl8[q] = *(const half8*)(Xlp + (jt * 16 + lr) * 256 + k0);
        }
        #pragma unroll
        for (int q = 0; q < 4; ++q)
            acc[q] = __builtin_amdgcn_mfma_f32_16x16x32_f16(ah, bh8[q], acc[q], 0, 0, 0);
        #pragma unroll
        for (int q = 0; q < 4; ++q)
            acc[q] = __builtin_amdgcn_mfma_f32_16x16x32_f16(ah, bl8[q], acc[q], 0, 0, 0);
        #pragma unroll
        for (int q = 0; q < 4; ++q)
            acc[q] = __builtin_amdgcn_mfma_f32_16x16x32_f16(al, bh8[q], acc[q], 0, 0, 0);
    }
    __shared__ float redS[4][16];
    float dp[4] = {0.f, 0.f, 0.f, 0.f};
    const float* Zp = Z + (bh * 256 + ibase) * 256;
    #pragma unroll
    for (int q = 0; q < 4; ++q) {
        const int jt = w * 4 + q;
        #pragma unroll
        for (int r = 0; r < 4; ++r)
            dp[r] += acc[q][r] * Zp[(ks * 4 + r) * 256 + jt * 16 + lr];
    }
    #pragma unroll
    for (int r = 0; r < 4; ++r) {
        float s = dp[r];
        s += __shfl_xor(s, 1); s += __shfl_xor(s, 2);
        s += __shfl_xor(s, 4); s += __shfl_xor(s, 8);
        if (lr == 0) redS[w][ks * 4 + r] = s;
    }
    __syncthreads();
    if (t < 16)
        Den[bh * 256 + ibase + t] =
            redS[0][t] + redS[1][t] + redS[2][t] + redS[3][t] + 1e-9f;
}

// ---------------------------------------------------------------------------
// Main contraction — FINAL (R16, verified best: attn 110 us, MfmaUtil 41%,
// 0 bank conflicts, total 169.4 us). BK=64, 4 steps x 192-MFMA bursts,
// reg-staged vk (VKLOAD->vkr->BSTORE, no cross-wave DMA hazard), B-dbuf in
// LDS with 16B-granule XOR swizzle, A sub-tile double-buffered from global.
// Plateau evidence (R17-R21 all neutral/worse): schedule permutations,
// barrier variants, barrier-free, 32x32 fragments — the kernel is
// latency-bound at the 2-wave/SIMD register ceiling (acc 128 + staging
// ~= 256 regs/wave, 3-pass f16 emulation fixes acc size). MFMA-pipe floor
// ~50 us; remaining gap is per-step staging chain with only 1 co-resident
// wave to hide it. Escapes measured and falsified: smaller acc (R9/R15:
// spill / smaller bursts), producer-consumer (R11/R12: vmcnt is per-wave,
// cross-wave DMA races), BSTORE-in-burst (R10/R17: spill / neutral).
// ---------------------------------------------------------------------------
__global__ __launch_bounds__(256, 2) void attn_mfma(
    const _Float16* __restrict__ Xh, const _Float16* __restrict__ Xl,
    const float* __restrict__ Yt, const float* __restrict__ Z,
    const float* __restrict__ vkT, const float* __restrict__ P32,
    const float* __restrict__ Den, float* __restrict__ out) {
    const int id = (blockIdx.x & 7) * 256 + (blockIdx.x >> 3);  // XCD swizzle
    const int bh = id >> 7;
    const int i0 = (id & 127) * 2;
    const int t = threadIdx.x;
    const int w = t >> 6, l = t & 63;
    const int lr = l & 15, ks = l >> 4, kk8 = ks * 8;

    __shared__ float yiS[2][256], ziS[2][256];                 // 4 KB
    __shared__ _Float16 BhS[2][2][4096], BlS[2][2][4096];      // 64 KB
    // redN aliases yiS (2 KB). Safe: last yiS read is BSTORE(3) in step 2,
    // which precedes step-2's __syncthreads; epilogue runs after that.
    float (*redN)[2][64] = reinterpret_cast<float (*)[2][64]>(&yiS[0][0]);

    yiS[0][t] = Yt[(bh * 256 + i0) * 256 + t];
    yiS[1][t] = Yt[(bh * 256 + i0 + 1) * 256 + t];
    ziS[0][t] = Z[(bh * 256 + i0) * 256 + t];
    ziS[1][t] = Z[(bh * 256 + i0 + 1) * 256 + t];

    const _Float16* Xhp = Xh + bh * 65536;
    const _Float16* Xlp = Xl + bh * 65536;
    const float* vkp = vkT + bh * 16384;
    const float* vj = P32 + (3 * 16 + bh) * 16384;

    floatx4 acc[4][8];
    #pragma unroll
    for (int mi = 0; mi < 4; ++mi)
        #pragma unroll
        for (int ct = 0; ct < 8; ++ct) acc[mi][ct] = (floatx4){0.f, 0.f, 0.f, 0.f};

    // VKLOAD/BSTORE thread map: d = t>>2 (64 rows), sl = t&3 (16-k slice)
    const int vd = t >> 2;
    const int sl = t & 3;
    float4 vkr[4];                        // in-flight vk slice (16 f32)

    // ---- VKLOAD: vk[vd][kt*64 + sl*16 .. +15] -> vkr (4 x dwordx4)
    auto VKLOAD = [&](int kt) {
        const float* gp = vkp + vd * 256 + (kt & 3) * 64 + sl * 16;
        #pragma unroll
        for (int q = 0; q < 4; ++q) vkr[q] = *(const float4*)(gp + q * 4);
    };
    // ---- BSTORE: vkr * y -> split -> swizzled BhS/BlS[(ktb)&1]
    auto BSTORE = [&](int ktb) {
        const int buf = ktb & 1;
        #pragma unroll
        for (int i = 0; i < 2; ++i) {
            const float* yrow = &yiS[i][(ktb & 3) * 64 + sl * 16];
            #pragma unroll
            for (int hq = 0; hq < 2; ++hq) {          // octet pair
                const float4 va = vkr[hq * 2], vb = vkr[hq * 2 + 1];
                const float4 ya = *(const float4*)(yrow + hq * 8);
                const float4 yb = *(const float4*)(yrow + hq * 8 + 4);
                const float pv[8] = {va.x * ya.x, va.y * ya.y, va.z * ya.z, va.w * ya.w,
                                     vb.x * yb.x, vb.y * yb.y, vb.z * yb.z, vb.w * yb.w};
                half8 hv, lv;
                #pragma unroll
                for (int e = 0; e < 8; ++e) {
                    _Float16 hh, ll;
                    split_f32(pv[e], hh, ll);
                    hv[e] = hh; lv[e] = ll;
                }
                const int o = sl * 2 + hq;            // k-octet 0..7 in 64-k tile
                const int g = vd * 8 + (o ^ (vd & 7));
                *(half8*)&BhS[buf][i][g * 8] = hv;
                *(half8*)&BlS[buf][i][g * 8] = lv;
            }
        }
    };
    auto LOADA = [&](half8* AH, half8* AL, int kt, int sub) {
        const int k0 = (kt & 3) * 64 + sub * 32 + kk8;
        #pragma unroll
        for (int mi = 0; mi < 4; ++mi) {
            const int row = w * 64 + mi * 16 + lr;
            AH[mi] = *(const half8*)(Xhp + row * 256 + k0);
            AL[mi] = *(const half8*)(Xlp + row * 256 + k0);
        }
    };
    auto MFMA_STEP = [&](half8* AH, half8* AL, int buf, int sub) {
        __builtin_amdgcn_s_setprio(1);
        #pragma unroll
        for (int ct = 0; ct < 8; ++ct) {
            const int ii = ct >> 2;
            const int dd = (ct & 3) * 16 + lr;
            const int o = sub * 4 + ks;
            const int g = dd * 8 + (o ^ (dd & 7));
            const half8 bhf = *(const half8*)&BhS[buf][ii][g * 8];
            const half8 blf = *(const half8*)&BlS[buf][ii][g * 8];
            #pragma unroll
            for (int mi = 0; mi < 4; ++mi)
                acc[mi][ct] = __builtin_amdgcn_mfma_f32_16x16x32_f16(AH[mi], bhf, acc[mi][ct], 0, 0, 0);
            #pragma unroll
            for (int mi = 0; mi < 4; ++mi)
                acc[mi][ct] = __builtin_amdgcn_mfma_f32_16x16x32_f16(AH[mi], blf, acc[mi][ct], 0, 0, 0);
            #pragma unroll
            for (int mi = 0; mi < 4; ++mi)
                acc[mi][ct] = __builtin_amdgcn_mfma_f32_16x16x32_f16(AL[mi], bhf, acc[mi][ct], 0, 0, 0);
        }
        __builtin_amdgcn_s_setprio(0);
    };

    half8 A0h[4], A0l[4], A1h[4], A1l[4];

    // ---- prologue: vk(0) in regs, A(0,sub0); build B(0)
    VKLOAD(0);                                   // 4 vmem
    LOADA(A0h, A0l, 0, 0);                       // 8 vmem
    asm volatile("s_waitcnt vmcnt(8)" ::: "memory");   // VKLOAD(0) + y/z loads done
    __builtin_amdgcn_sched_barrier(0);
    __syncthreads();                             // y/z ds_writes drained + visible
    BSTORE(0);
    __syncthreads();                             // B(0) visible

    // ---- main loop: steps 0..2 full; step 3 tail
    #pragma unroll 1
    for (int kt = 0; kt < 3; ++kt) {
        const int buf = kt & 1;
        VKLOAD(kt + 1);                          // 4 vmem
        LOADA(A1h, A1l, kt, 1);                  // 8 vmem
        MFMA_STEP(A0h, A0l, buf, 0);             // A0 from prev step (auto-wait)
        LOADA(A0h, A0l, kt + 1, 0);              // 8 vmem (next step's sub0)
        MFMA_STEP(A1h, A1l, buf, 1);             // A1 covered by sub0 burst
        asm volatile("s_waitcnt vmcnt(16)" ::: "memory");  // VKLOAD(kt+1) done
        __builtin_amdgcn_sched_barrier(0);
        BSTORE(kt + 1);                          // writes BhS[buf^1]
        __syncthreads();
    }
    // tail: kt = 3 (buf 1)
    LOADA(A1h, A1l, 3, 1);
    MFMA_STEP(A0h, A0l, 1, 0);
    MFMA_STEP(A1h, A1l, 1, 1);

    // ---- epilogue
    float z0[16], z1[16];
    #pragma unroll
    for (int mi = 0; mi < 4; ++mi)
        #pragma unroll
        for (int r = 0; r < 4; ++r) {
            const int j = w * 64 + mi * 16 + ks * 4 + r;
            z0[mi * 4 + r] = ziS[0][j];
            z1[mi * 4 + r] = ziS[1][j];
        }
    #pragma unroll
    for (int dt = 0; dt < 4; ++dt) {
        float n0 = 0.f, n1 = 0.f;
        #pragma unroll
        for (int mi = 0; mi < 4; ++mi)
            #pragma unroll
            for (int r = 0; r < 4; ++r) {
                const int j = w * 64 + mi * 16 + ks * 4 + r;
                const float v = vj[j * 64 + dt * 16 + lr];
                n0 += acc[mi][dt][r] * z0[mi * 4 + r] * v;
                n1 += acc[mi][dt + 4][r] * z1[mi * 4 + r] * v;
            }
        n0 += __shfl_xor(n0, 16); n0 += __shfl_xor(n0, 32);
        n1 += __shfl_xor(n1, 16); n1 += __shfl_xor(n1, 32);
        if (l < 16) {
            redN[w][0][dt * 16 + l] = n0;
            redN[w][1][dt * 16 + l] = n1;
        }
    }
    __syncthreads();
    if (t < 128) {
        const int ih = t >> 6, d = t & 63;
        const float num = redN[0][ih][d] + redN[1][ih][d] +
                          redN[2][ih][d] + redN[3][ih][d];
        const int i = i0 + ih;
        const float den = Den[bh * 256 + i];
        out[((bh >> 3) * 256 + i) * 512 + (bh & 7) * 64 + d] = num / den;
    }
}

extern "C" void kernel_launch(void* const* d_in, const int* in_sizes, int n_in,
                              void* d_out, int out_size, void* d_ws, size_t ws_size,
                              hipStream_t stream) {
    const float* x = (const float*)d_in[0];
    const float* w = (const float*)d_in[1];
    float* out = (float*)d_out;

    float* ws = (float*)d_ws;
    float* P32 = ws;                                    // 1,310,720 f32
    float* U = ws + 1310720;
    // epoch A (proj inputs, dead after proj):
    _Float16* xh = (_Float16*)U;
    _Float16* xl = xh + 262144;
    _Float16* wh = xl + 262144;
    _Float16* wl = wh + 1310720;
    // epoch B (score onward):
    _Float16* Xsh = (_Float16*)U;                       // 1,048,576 h
    _Float16* Xsl = Xsh + 1048576;
    float* Yt = U + 1048576;                            // 1,048,576 f32
    float* Z = Yt + 1048576;                            // 1,048,576 f32
    float* vkT = Z + 1048576;                           // 262,144 f32 (written by proj)
    float* Den = vkT + 262144;                          // 4,096 f32

    split2_kernel<<<1536, 256, 0, stream>>>(x, w, xh, xl, wh, wl);
    proj_mfma<<<dim3(8, 40), 256, 0, stream>>>(xh, xl, wh, wl, P32, vkT);
    score_vkt<<<dim3(16, 3, 8), 256, 0, stream>>>(P32, Xsh, Xsl, Yt, Z);
    den_mfma<<<dim3(16, 16), 256, 0, stream>>>(Yt, Xsh, Xsl, Z, Den);
    attn_mfma<<<2048, 256, 0, stream>>>(Xsh, Xsl, Yt, Z, vkT, P32, Den, out);
}